// Round 2
// baseline (596.409 us; speedup 1.0000x reference)
//
#include <hip/hip_runtime.h>

// ---------------------------------------------------------------------------
// LSTM (H=2, I=4, T=10) + MLP 20->128->64->32->1, fp32, B=1M elements.
// One thread per batch element. All weights are wave-uniform -> SGPR s_loads.
// L1->L2 fused as scatter over k (needs W2 transposed, staged in d_ws).
// All register arrays statically indexed (full unroll where required).
// ---------------------------------------------------------------------------

__device__ __forceinline__ float fsig(float x) {
    // 1/(1+e^-x); v_exp + v_rcp, rel err ~1e-7 -- fine vs 1e-3 threshold
    return __builtin_amdgcn_rcpf(1.0f + __expf(-x));
}
__device__ __forceinline__ float ftanh(float x) {
    // 1 - 2/(e^{2x}+1); correct saturation at +/-inf
    return 1.0f - 2.0f * __builtin_amdgcn_rcpf(__expf(2.0f * x) + 1.0f);
}

// Prep: W2 [64][128] -> W2T [128][64] so the fused scatter loop reads
// contiguous 64-float rows via s_load_dwordx16.
__global__ void w2_transpose_kernel(const float* __restrict__ W2,
                                    float* __restrict__ W2T) {
    int idx = blockIdx.x * blockDim.x + threadIdx.x;
    if (idx < 64 * 128) {
        int j = idx >> 7;    // W2 row (output neuron) 0..63
        int k = idx & 127;   // W2 col (input) 0..127
        W2T[k * 64 + j] = W2[idx];
    }
}

__global__ __launch_bounds__(256) void lstm_mlp_fused(
    const float* __restrict__ x,
    const float* __restrict__ W_ih, const float* __restrict__ W_hh,
    const float* __restrict__ b_ih, const float* __restrict__ b_hh,
    const float* __restrict__ W1,   const float* __restrict__ b1,
    const float* __restrict__ W2T,  const float* __restrict__ b2,
    const float* __restrict__ W3,   const float* __restrict__ b3,
    const float* __restrict__ W4,   const float* __restrict__ b4,
    float* __restrict__ out, int B)
{
    const int b = blockIdx.x * blockDim.x + threadIdx.x;
    if (b >= B) return;

    // ---------------- LSTM ----------------
    // Weights: uniform, compile-time indices -> SGPRs.
    float wih[8][4], whh[8][2], bias[8];
#pragma unroll
    for (int k = 0; k < 8; ++k) {
#pragma unroll
        for (int i = 0; i < 4; ++i) wih[k][i] = W_ih[k * 4 + i];
        whh[k][0] = W_hh[k * 2 + 0];
        whh[k][1] = W_hh[k * 2 + 1];
        bias[k] = b_ih[k] + b_hh[k];
    }

    const float4* xb = reinterpret_cast<const float4*>(x) + (size_t)b * 10;

    float h0 = 0.0f, h1 = 0.0f, c0 = 0.0f, c1 = 0.0f;
    float hist[20];  // h over time, static-indexed (t unrolled)
#pragma unroll
    for (int t = 0; t < 10; ++t) {
        const float4 xv = xb[t];
        float g[8];
#pragma unroll
        for (int k = 0; k < 8; ++k) {
            float a = bias[k];
            a = fmaf(wih[k][0], xv.x, a);
            a = fmaf(wih[k][1], xv.y, a);
            a = fmaf(wih[k][2], xv.z, a);
            a = fmaf(wih[k][3], xv.w, a);
            a = fmaf(whh[k][0], h0, a);
            a = fmaf(whh[k][1], h1, a);
            g[k] = a;
        }
        // pytorch gate order: i, f, g, o (each H=2 wide)
        const float i0 = fsig(g[0]), i1 = fsig(g[1]);
        const float f0 = fsig(g[2]), f1 = fsig(g[3]);
        const float gg0 = ftanh(g[4]), gg1 = ftanh(g[5]);
        const float o0 = fsig(g[6]), o1 = fsig(g[7]);
        c0 = fmaf(f0, c0, i0 * gg0);
        c1 = fmaf(f1, c1, i1 * gg1);
        h0 = o0 * ftanh(c0);
        h1 = o1 * ftanh(c1);
        hist[t * 2 + 0] = h0;
        hist[t * 2 + 1] = h1;
    }

    // ---------------- MLP ----------------
    // Fused L1->L2: dynamic uniform loop over the 128 L1 neurons; each
    // iteration computes one ReLU'd a1 value (static hist reads, uniform
    // s_load weights) and scatters into statically-indexed a2[64].
    float a2[64];
#pragma unroll
    for (int j = 0; j < 64; ++j) a2[j] = b2[j];

#pragma unroll 2
    for (int k = 0; k < 128; ++k) {
        const float* w1r = W1 + k * 20;
        float s0 = 0.0f, s1 = 0.0f;  // two chains for ILP
#pragma unroll
        for (int i = 0; i < 20; i += 2) {
            s0 = fmaf(hist[i + 0], w1r[i + 0], s0);
            s1 = fmaf(hist[i + 1], w1r[i + 1], s1);
        }
        const float a = fmaxf(s0 + s1 + b1[k], 0.0f);
        const float* w2c = W2T + k * 64;
#pragma unroll
        for (int j = 0; j < 64; ++j) a2[j] = fmaf(a, w2c[j], a2[j]);
    }
#pragma unroll
    for (int j = 0; j < 64; ++j) a2[j] = fmaxf(a2[j], 0.0f);

    // L3 (64->32) + L4 (32->1), fully unrolled to keep a2/a3 in registers.
    float a3[32];
#pragma unroll
    for (int j = 0; j < 32; ++j) {
        float acc = b3[j];
        const float* w3r = W3 + j * 64;
#pragma unroll
        for (int k = 0; k < 64; ++k) acc = fmaf(a2[k], w3r[k], acc);
        a3[j] = fmaxf(acc, 0.0f);
    }

    float o = b4[0];
#pragma unroll
    for (int k = 0; k < 32; ++k) o = fmaf(a3[k], W4[k], o);

    out[b] = o;
}

extern "C" void kernel_launch(void* const* d_in, const int* in_sizes, int n_in,
                              void* d_out, int out_size, void* d_ws, size_t ws_size,
                              hipStream_t stream) {
    const float* x    = (const float*)d_in[0];
    const float* W_ih = (const float*)d_in[1];
    const float* W_hh = (const float*)d_in[2];
    const float* b_ih = (const float*)d_in[3];
    const float* b_hh = (const float*)d_in[4];
    const float* W1   = (const float*)d_in[5];
    const float* b1   = (const float*)d_in[6];
    const float* W2   = (const float*)d_in[7];
    const float* b2   = (const float*)d_in[8];
    const float* W3   = (const float*)d_in[9];
    const float* b3   = (const float*)d_in[10];
    const float* W4   = (const float*)d_in[11];
    const float* b4   = (const float*)d_in[12];
    float* out = (float*)d_out;

    float* W2T = (float*)d_ws;  // 128*64 floats = 32 KB scratch

    hipLaunchKernelGGL(w2_transpose_kernel, dim3(32), dim3(256), 0, stream, W2, W2T);

    const int B = in_sizes[0] / 40;  // [B, T=10, I=4]
    const int grid = (B + 255) / 256;
    hipLaunchKernelGGL(lstm_mlp_fused, dim3(grid), dim3(256), 0, stream,
                       x, W_ih, W_hh, b_ih, b_hh, W1, b1, W2T, b2, W3, b3,
                       W4, b4, out, B);
}

// Round 3
// 342.250 us; speedup vs baseline: 1.7426x; 1.7426x over previous
//
#include <hip/hip_runtime.h>

// ---------------------------------------------------------------------------
// LSTM (H=2,I=4,T=10) on VALU + MLP 20->128->64->32->1 on MFMA (split-bf16).
// One thread per element; each wave owns 64 rows (M=64).
// MLP GEMMs: D = A(act) x B(weights), mfma_f32_16x16x32_bf16, 3 mfma/tile
// (Ah*Bh + Ah*Bl + Al*Bh). Weights pre-split + pre-fragmented into d_ws.
// Inter-layer transpose via per-wave LDS buffer T (wave-local, lgkm fences).
// Verified-layout assumptions (learn_hip m89/m92): A-frag lane l elem j =
// A[l&15][8*(l>>4)+j]; B-frag = B[8*(l>>4)+j][l&15]; D lane l reg r =
// D[4*(l>>4)+r][l&15].
// ---------------------------------------------------------------------------

typedef __attribute__((ext_vector_type(8))) short bf16x8;
typedef __attribute__((ext_vector_type(4))) float f32x4;

__device__ __forceinline__ float fsig(float x) { return __builtin_amdgcn_rcpf(1.0f + __expf(-x)); }
__device__ __forceinline__ float ftanh(float x) { return 1.0f - 2.0f * __builtin_amdgcn_rcpf(__expf(2.0f * x) + 1.0f); }

__device__ __forceinline__ unsigned short bf16_rne(float v) {
    union { float f; unsigned u; } cv; cv.f = v;
    unsigned r = (cv.u + 0x7fffu + ((cv.u >> 16) & 1u)) >> 16;
    return (unsigned short)r;
}
__device__ __forceinline__ float bf16_f(unsigned short h) {
    union { unsigned u; float f; } cv; cv.u = ((unsigned)h) << 16; return cv.f;
}
__device__ __forceinline__ f32x4 mm(bf16x8 a, bf16x8 b, f32x4 c) {
    return __builtin_amdgcn_mfma_f32_16x16x32_bf16(a, b, c, 0, 0, 0);
}

// --- prep: split W1/W2/W3 into hi/lo bf16 B-fragments in ws ---
// layout (shorts): w1f [8nt][2pl][64][8] @0 (8192)
//                  w2f [4kt][4nt][2pl][64][8] @8192 (16384)
//                  w3f [2kt][2nt][2pl][64][8] @24576 (4096)   total 28672
__global__ void prep_frags(const float* __restrict__ W1,
                           const float* __restrict__ W2,
                           const float* __restrict__ W3,
                           unsigned short* __restrict__ wf) {
    int idx = blockIdx.x * 256 + threadIdx.x;
    if (idx >= 28672) return;
    float v = 0.0f; int pl;
    if (idx < 8192) {
        int r = idx;
        int j = r & 7, lane = (r >> 3) & 63; pl = (r >> 9) & 1; int nt = r >> 10;
        int cc = lane & 15, gg = lane >> 4;
        int k = 8 * gg + j, n = nt * 16 + cc;
        v = (k < 20) ? W1[n * 20 + k] : 0.0f;   // K padded 20->32 with zeros
    } else if (idx < 24576) {
        int r = idx - 8192;
        int j = r & 7, lane = (r >> 3) & 63; pl = (r >> 9) & 1;
        int nt = (r >> 10) & 3, kt = r >> 12;
        int cc = lane & 15, gg = lane >> 4;
        int k = kt * 32 + 8 * gg + j, n = nt * 16 + cc;
        v = W2[n * 128 + k];
    } else {
        int r = idx - 24576;
        int j = r & 7, lane = (r >> 3) & 63; pl = (r >> 9) & 1;
        int nt = (r >> 10) & 1, kt = r >> 11;
        int cc = lane & 15, gg = lane >> 4;
        int k = kt * 32 + 8 * gg + j, n = nt * 16 + cc;
        v = W3[n * 64 + k];
    }
    unsigned short hi = bf16_rne(v);
    unsigned short lo = bf16_rne(v - bf16_f(hi));
    wf[idx] = pl ? lo : hi;
}

__global__ __launch_bounds__(256, 3) void lstm_mlp_mfma(
    const float* __restrict__ x,
    const float* __restrict__ W_ih, const float* __restrict__ W_hh,
    const float* __restrict__ b_ih, const float* __restrict__ b_hh,
    const unsigned short* __restrict__ wf,
    const float* __restrict__ b1, const float* __restrict__ b2,
    const float* __restrict__ b3,
    const float* __restrict__ W4, const float* __restrict__ b4,
    float* __restrict__ out)
{
    // per-wave transpose buffer: [plane][row][40] shorts; 10240 B/wave
    __shared__ unsigned short T[4][2][64][40];
    const int tid = threadIdx.x;
    const int w = tid >> 6, lane = tid & 63;
    const int c = lane & 15, g = lane >> 4;
    const long long b = (long long)blockIdx.x * 256 + tid;

    // ---------------- LSTM (VALU, identical math to verified baseline) ----
    float wih[8][4], whh[8][2], lbias[8];
#pragma unroll
    for (int k = 0; k < 8; ++k) {
#pragma unroll
        for (int i = 0; i < 4; ++i) wih[k][i] = W_ih[k * 4 + i];
        whh[k][0] = W_hh[k * 2 + 0];
        whh[k][1] = W_hh[k * 2 + 1];
        lbias[k] = b_ih[k] + b_hh[k];
    }
    const float4* xb = reinterpret_cast<const float4*>(x) + b * 10;
    float h0 = 0.0f, h1 = 0.0f, c0 = 0.0f, c1v = 0.0f;
    float hist[20];
#pragma unroll
    for (int t = 0; t < 10; ++t) {
        const float4 xv = xb[t];
        float gg[8];
#pragma unroll
        for (int k = 0; k < 8; ++k) {
            float a = lbias[k];
            a = fmaf(wih[k][0], xv.x, a);
            a = fmaf(wih[k][1], xv.y, a);
            a = fmaf(wih[k][2], xv.z, a);
            a = fmaf(wih[k][3], xv.w, a);
            a = fmaf(whh[k][0], h0, a);
            a = fmaf(whh[k][1], h1, a);
            gg[k] = a;
        }
        const float i0 = fsig(gg[0]), i1 = fsig(gg[1]);
        const float f0 = fsig(gg[2]), f1 = fsig(gg[3]);
        const float g0 = ftanh(gg[4]), g1 = ftanh(gg[5]);
        const float o0 = fsig(gg[6]), o1 = fsig(gg[7]);
        c0 = fmaf(f0, c0, i0 * g0);
        c1v = fmaf(f1, c1v, i1 * g1);
        h0 = o0 * ftanh(c0);
        h1 = o1 * ftanh(c1v);
        hist[t * 2 + 0] = h0;
        hist[t * 2 + 1] = h1;
    }

    // ---------------- stage hist rows (split bf16, K=32 zero-padded) ------
#pragma unroll
    for (int i = 0; i < 10; ++i) {
        unsigned short hA = bf16_rne(hist[2 * i]);
        unsigned short hB = bf16_rne(hist[2 * i + 1]);
        unsigned short lA = bf16_rne(hist[2 * i] - bf16_f(hA));
        unsigned short lB = bf16_rne(hist[2 * i + 1] - bf16_f(hB));
        *(unsigned*)&T[w][0][lane][2 * i] = (unsigned)hA | ((unsigned)hB << 16);
        *(unsigned*)&T[w][1][lane][2 * i] = (unsigned)lA | ((unsigned)lB << 16);
    }
#pragma unroll
    for (int i = 0; i < 6; ++i) {
        *(unsigned*)&T[w][0][lane][20 + 2 * i] = 0u;
        *(unsigned*)&T[w][1][lane][20 + 2 * i] = 0u;
    }
    asm volatile("s_waitcnt lgkmcnt(0)" ::: "memory");

    // A1 fragments held in registers for all chunks
    bf16x8 a1h[4], a1l[4];
#pragma unroll
    for (int mt = 0; mt < 4; ++mt) {
        a1h[mt] = *(const bf16x8*)&T[w][0][mt * 16 + c][8 * g];
        a1l[mt] = *(const bf16x8*)&T[w][1][mt * 16 + c][8 * g];
    }
    asm volatile("s_waitcnt lgkmcnt(0)" ::: "memory");

    const unsigned short* w1f = wf;
    const unsigned short* w2f = wf + 8192;
    const unsigned short* w3f = wf + 24576;
    const f32x4 zero4 = {0.f, 0.f, 0.f, 0.f};

    f32x4 acc2[4][4];
#pragma unroll
    for (int mt = 0; mt < 4; ++mt)
#pragma unroll
        for (int nt = 0; nt < 4; ++nt) acc2[mt][nt] = zero4;

    // ---------------- L1 (chunked) + L2 accumulate ------------------------
#pragma unroll
    for (int ch = 0; ch < 4; ++ch) {
        // L1 for cols [ch*32, ch*32+32) -> transpose buffer
#pragma unroll
        for (int ct = 0; ct < 2; ++ct) {
            const int nt1 = ch * 2 + ct;
            bf16x8 wh = *(const bf16x8*)&w1f[((nt1 * 2 + 0) * 64 + lane) * 8];
            bf16x8 wl = *(const bf16x8*)&w1f[((nt1 * 2 + 1) * 64 + lane) * 8];
            const float bias1 = b1[nt1 * 16 + c];
#pragma unroll
            for (int mt = 0; mt < 4; ++mt) {
                f32x4 c1 = zero4;
                c1 = mm(a1h[mt], wh, c1);
                c1 = mm(a1h[mt], wl, c1);
                c1 = mm(a1l[mt], wh, c1);
#pragma unroll
                for (int rr = 0; rr < 4; ++rr) {
                    float v = fmaxf(c1[rr] + bias1, 0.0f);
                    unsigned short h = bf16_rne(v);
                    unsigned short l = bf16_rne(v - bf16_f(h));
                    T[w][0][mt * 16 + 4 * g + rr][ct * 16 + c] = h;
                    T[w][1][mt * 16 + 4 * g + rr][ct * 16 + c] = l;
                }
            }
        }
        asm volatile("s_waitcnt lgkmcnt(0)" ::: "memory");
        // L2 partial: K-chunk = ch
        bf16x8 w2h[4], w2l[4];
#pragma unroll
        for (int nt = 0; nt < 4; ++nt) {
            w2h[nt] = *(const bf16x8*)&w2f[(((ch * 4 + nt) * 2 + 0) * 64 + lane) * 8];
            w2l[nt] = *(const bf16x8*)&w2f[(((ch * 4 + nt) * 2 + 1) * 64 + lane) * 8];
        }
#pragma unroll
        for (int mt = 0; mt < 4; ++mt) {
            bf16x8 ah = *(const bf16x8*)&T[w][0][mt * 16 + c][8 * g];
            bf16x8 al = *(const bf16x8*)&T[w][1][mt * 16 + c][8 * g];
#pragma unroll
            for (int nt = 0; nt < 4; ++nt) {
                acc2[mt][nt] = mm(ah, w2h[nt], acc2[mt][nt]);
                acc2[mt][nt] = mm(ah, w2l[nt], acc2[mt][nt]);
                acc2[mt][nt] = mm(al, w2h[nt], acc2[mt][nt]);
            }
        }
        asm volatile("s_waitcnt lgkmcnt(0)" ::: "memory");
    }

    // ---------------- L3 (two K-chunks from acc2) -------------------------
    f32x4 acc3[4][2];
#pragma unroll
    for (int mt = 0; mt < 4; ++mt) { acc3[mt][0] = zero4; acc3[mt][1] = zero4; }

#pragma unroll
    for (int kc = 0; kc < 2; ++kc) {
#pragma unroll
        for (int q = 0; q < 2; ++q) {
            const int nt2 = kc * 2 + q;
            const float bias2 = b2[nt2 * 16 + c];
#pragma unroll
            for (int mt = 0; mt < 4; ++mt) {
#pragma unroll
                for (int rr = 0; rr < 4; ++rr) {
                    float v = fmaxf(acc2[mt][nt2][rr] + bias2, 0.0f);
                    unsigned short h = bf16_rne(v);
                    unsigned short l = bf16_rne(v - bf16_f(h));
                    T[w][0][mt * 16 + 4 * g + rr][q * 16 + c] = h;
                    T[w][1][mt * 16 + 4 * g + rr][q * 16 + c] = l;
                }
            }
        }
        asm volatile("s_waitcnt lgkmcnt(0)" ::: "memory");
        bf16x8 w3h[2], w3l[2];
#pragma unroll
        for (int nt = 0; nt < 2; ++nt) {
            w3h[nt] = *(const bf16x8*)&w3f[(((kc * 2 + nt) * 2 + 0) * 64 + lane) * 8];
            w3l[nt] = *(const bf16x8*)&w3f[(((kc * 2 + nt) * 2 + 1) * 64 + lane) * 8];
        }
#pragma unroll
        for (int mt = 0; mt < 4; ++mt) {
            bf16x8 ah = *(const bf16x8*)&T[w][0][mt * 16 + c][8 * g];
            bf16x8 al = *(const bf16x8*)&T[w][1][mt * 16 + c][8 * g];
#pragma unroll
            for (int nt = 0; nt < 2; ++nt) {
                acc3[mt][nt] = mm(ah, w3h[nt], acc3[mt][nt]);
                acc3[mt][nt] = mm(ah, w3l[nt], acc3[mt][nt]);
                acc3[mt][nt] = mm(al, w3h[nt], acc3[mt][nt]);
            }
        }
        asm volatile("s_waitcnt lgkmcnt(0)" ::: "memory");
    }

    // ---------------- L3 relu -> f32 LDS -> per-thread L4 -----------------
    float* a3f = (float*)&T[w][0][0][0];  // [64][36] f32 view (9216 B)
#pragma unroll
    for (int nt = 0; nt < 2; ++nt) {
        const float bias3 = b3[nt * 16 + c];
#pragma unroll
        for (int mt = 0; mt < 4; ++mt)
#pragma unroll
            for (int rr = 0; rr < 4; ++rr)
                a3f[(mt * 16 + 4 * g + rr) * 36 + nt * 16 + c] =
                    fmaxf(acc3[mt][nt][rr] + bias3, 0.0f);
    }
    asm volatile("s_waitcnt lgkmcnt(0)" ::: "memory");
    float o = b4[0];
#pragma unroll
    for (int k = 0; k < 32; ++k) o = fmaf(a3f[lane * 36 + k], W4[k], o);
    out[b] = o;
}

extern "C" void kernel_launch(void* const* d_in, const int* in_sizes, int n_in,
                              void* d_out, int out_size, void* d_ws, size_t ws_size,
                              hipStream_t stream) {
    const float* x    = (const float*)d_in[0];
    const float* W_ih = (const float*)d_in[1];
    const float* W_hh = (const float*)d_in[2];
    const float* b_ih = (const float*)d_in[3];
    const float* b_hh = (const float*)d_in[4];
    const float* W1   = (const float*)d_in[5];
    const float* b1   = (const float*)d_in[6];
    const float* W2   = (const float*)d_in[7];
    const float* b2   = (const float*)d_in[8];
    const float* W3   = (const float*)d_in[9];
    const float* b3   = (const float*)d_in[10];
    const float* W4   = (const float*)d_in[11];
    const float* b4   = (const float*)d_in[12];
    float* out = (float*)d_out;

    unsigned short* wf = (unsigned short*)d_ws;  // 28672 shorts = 57344 B

    hipLaunchKernelGGL(prep_frags, dim3(112), dim3(256), 0, stream, W1, W2, W3, wf);

    const int B = in_sizes[0] / 40;  // [B, 10, 4]
    hipLaunchKernelGGL(lstm_mlp_mfma, dim3(B / 256), dim3(256), 0, stream,
                       x, W_ih, W_hh, b_ih, b_hh, wf, b1, b2, b3, W4, b4, out);
}

// Round 5
// 329.195 us; speedup vs baseline: 1.8117x; 1.0397x over previous
//
#include <hip/hip_runtime.h>
#include <hip/hip_bf16.h>

// ---------------------------------------------------------------------------
// LSTM (H=2,I=4,T=10) on VALU + MLP 20->128->64->32->1 on MFMA (split-bf16).
// One thread per element; each wave owns 64 rows (M=64).
// MLP GEMMs: D = A(act) x B(weights), mfma_f32_16x16x32_bf16, 3 mfma/tile
// (Ah*Bh + Ah*Bl + Al*Bh). Weights pre-split + pre-fragmented into d_ws.
// Inter-layer transpose via per-wave LDS buffer T (wave-local, lgkm fences).
// R4 change: native v_cvt bf16 conversions (was ~10-op software RNE) and
// conflict-free L4 stride. Structure/numerics otherwise identical to R3.
// ---------------------------------------------------------------------------

typedef __attribute__((ext_vector_type(8))) short bf16x8;
typedef __attribute__((ext_vector_type(4))) float f32x4;

__device__ __forceinline__ float fsig(float x) { return __builtin_amdgcn_rcpf(1.0f + __expf(-x)); }
__device__ __forceinline__ float ftanh(float x) { return 1.0f - 2.0f * __builtin_amdgcn_rcpf(__expf(2.0f * x) + 1.0f); }

__device__ __forceinline__ unsigned short bf_bits(__hip_bfloat16 h) {
    union { __hip_bfloat16 b; unsigned short u; } cv; cv.b = h; return cv.u;
}
// split v into hi(bf16) + lo(bf16), native cvt (RNE) — ~4 VALU ops
__device__ __forceinline__ void split2(float v, unsigned short& h, unsigned short& l) {
    __hip_bfloat16 hb = __float2bfloat16(v);
    float hf = __bfloat162float(hb);
    h = bf_bits(hb);
    l = bf_bits(__float2bfloat16(v - hf));
}
__device__ __forceinline__ f32x4 mm(bf16x8 a, bf16x8 b, f32x4 c) {
    return __builtin_amdgcn_mfma_f32_16x16x32_bf16(a, b, c, 0, 0, 0);
}

// --- prep: split W1/W2/W3 into hi/lo bf16 B-fragments in ws ---
// layout (shorts): w1f [8nt][2pl][64][8] @0 (8192)
//                  w2f [4kt][4nt][2pl][64][8] @8192 (16384)
//                  w3f [2kt][2nt][2pl][64][8] @24576 (4096)   total 28672
__global__ void prep_frags(const float* __restrict__ W1,
                           const float* __restrict__ W2,
                           const float* __restrict__ W3,
                           unsigned short* __restrict__ wf) {
    int idx = blockIdx.x * 256 + threadIdx.x;
    if (idx >= 28672) return;
    float v = 0.0f; int pl;
    if (idx < 8192) {
        int r = idx;
        int j = r & 7, lane = (r >> 3) & 63; pl = (r >> 9) & 1; int nt = r >> 10;
        int cc = lane & 15, gg = lane >> 4;
        int k = 8 * gg + j, n = nt * 16 + cc;
        v = (k < 20) ? W1[n * 20 + k] : 0.0f;   // K padded 20->32 with zeros
    } else if (idx < 24576) {
        int r = idx - 8192;
        int j = r & 7, lane = (r >> 3) & 63; pl = (r >> 9) & 1;
        int nt = (r >> 10) & 3, kt = r >> 12;
        int cc = lane & 15, gg = lane >> 4;
        int k = kt * 32 + 8 * gg + j, n = nt * 16 + cc;
        v = W2[n * 128 + k];
    } else {
        int r = idx - 24576;
        int j = r & 7, lane = (r >> 3) & 63; pl = (r >> 9) & 1;
        int nt = (r >> 10) & 1, kt = r >> 11;
        int cc = lane & 15, gg = lane >> 4;
        int k = kt * 32 + 8 * gg + j, n = nt * 16 + cc;
        v = W3[n * 64 + k];
    }
    unsigned short hi, lo;
    split2(v, hi, lo);
    wf[idx] = pl ? lo : hi;
}

__global__ __launch_bounds__(256, 3) void lstm_mlp_mfma(
    const float* __restrict__ x,
    const float* __restrict__ W_ih, const float* __restrict__ W_hh,
    const float* __restrict__ b_ih, const float* __restrict__ b_hh,
    const unsigned short* __restrict__ wf,
    const float* __restrict__ b1, const float* __restrict__ b2,
    const float* __restrict__ b3,
    const float* __restrict__ W4, const float* __restrict__ b4,
    float* __restrict__ out)
{
    // per-wave transpose buffer: [plane][row][40] shorts; 10240 B/wave
    __shared__ unsigned short T[4][2][64][40];
    const int tid = threadIdx.x;
    const int w = tid >> 6, lane = tid & 63;
    const int c = lane & 15, g = lane >> 4;
    const long long b = (long long)blockIdx.x * 256 + tid;

    // ---------------- LSTM (VALU, identical math to verified baseline) ----
    float wih[8][4], whh[8][2], lbias[8];
#pragma unroll
    for (int k = 0; k < 8; ++k) {
#pragma unroll
        for (int i = 0; i < 4; ++i) wih[k][i] = W_ih[k * 4 + i];
        whh[k][0] = W_hh[k * 2 + 0];
        whh[k][1] = W_hh[k * 2 + 1];
        lbias[k] = b_ih[k] + b_hh[k];
    }
    const float4* xb = reinterpret_cast<const float4*>(x) + b * 10;
    float h0 = 0.0f, h1 = 0.0f, c0 = 0.0f, c1v = 0.0f;
    float hist[20];
#pragma unroll
    for (int t = 0; t < 10; ++t) {
        const float4 xv = xb[t];
        float gg[8];
#pragma unroll
        for (int k = 0; k < 8; ++k) {
            float a = lbias[k];
            a = fmaf(wih[k][0], xv.x, a);
            a = fmaf(wih[k][1], xv.y, a);
            a = fmaf(wih[k][2], xv.z, a);
            a = fmaf(wih[k][3], xv.w, a);
            a = fmaf(whh[k][0], h0, a);
            a = fmaf(whh[k][1], h1, a);
            gg[k] = a;
        }
        const float i0 = fsig(gg[0]), i1 = fsig(gg[1]);
        const float f0 = fsig(gg[2]), f1 = fsig(gg[3]);
        const float g0 = ftanh(gg[4]), g1 = ftanh(gg[5]);
        const float o0 = fsig(gg[6]), o1 = fsig(gg[7]);
        c0 = fmaf(f0, c0, i0 * g0);
        c1v = fmaf(f1, c1v, i1 * g1);
        h0 = o0 * ftanh(c0);
        h1 = o1 * ftanh(c1v);
        hist[t * 2 + 0] = h0;
        hist[t * 2 + 1] = h1;
    }

    // ---------------- stage hist rows (split bf16, K=32 zero-padded) ------
#pragma unroll
    for (int i = 0; i < 10; ++i) {
        unsigned short hA, lA, hB, lB;
        split2(hist[2 * i], hA, lA);
        split2(hist[2 * i + 1], hB, lB);
        *(unsigned*)&T[w][0][lane][2 * i] = (unsigned)hA | ((unsigned)hB << 16);
        *(unsigned*)&T[w][1][lane][2 * i] = (unsigned)lA | ((unsigned)lB << 16);
    }
#pragma unroll
    for (int i = 0; i < 6; ++i) {
        *(unsigned*)&T[w][0][lane][20 + 2 * i] = 0u;
        *(unsigned*)&T[w][1][lane][20 + 2 * i] = 0u;
    }
    asm volatile("s_waitcnt lgkmcnt(0)" ::: "memory");

    // A1 fragments held in registers for all chunks
    bf16x8 a1h[4], a1l[4];
#pragma unroll
    for (int mt = 0; mt < 4; ++mt) {
        a1h[mt] = *(const bf16x8*)&T[w][0][mt * 16 + c][8 * g];
        a1l[mt] = *(const bf16x8*)&T[w][1][mt * 16 + c][8 * g];
    }
    asm volatile("s_waitcnt lgkmcnt(0)" ::: "memory");

    const unsigned short* w1f = wf;
    const unsigned short* w2f = wf + 8192;
    const unsigned short* w3f = wf + 24576;
    const f32x4 zero4 = {0.f, 0.f, 0.f, 0.f};

    f32x4 acc2[4][4];
#pragma unroll
    for (int mt = 0; mt < 4; ++mt)
#pragma unroll
        for (int nt = 0; nt < 4; ++nt) acc2[mt][nt] = zero4;

    // ---------------- L1 (chunked) + L2 accumulate ------------------------
#pragma unroll
    for (int ch = 0; ch < 4; ++ch) {
        // L1 for cols [ch*32, ch*32+32) -> transpose buffer
#pragma unroll
        for (int ct = 0; ct < 2; ++ct) {
            const int nt1 = ch * 2 + ct;
            bf16x8 wh = *(const bf16x8*)&w1f[((nt1 * 2 + 0) * 64 + lane) * 8];
            bf16x8 wl = *(const bf16x8*)&w1f[((nt1 * 2 + 1) * 64 + lane) * 8];
            const float bias1 = b1[nt1 * 16 + c];
#pragma unroll
            for (int mt = 0; mt < 4; ++mt) {
                f32x4 c1 = zero4;
                c1 = mm(a1h[mt], wh, c1);
                c1 = mm(a1h[mt], wl, c1);
                c1 = mm(a1l[mt], wh, c1);
#pragma unroll
                for (int rr = 0; rr < 4; ++rr) {
                    float v = fmaxf(c1[rr] + bias1, 0.0f);
                    unsigned short h, l;
                    split2(v, h, l);
                    T[w][0][mt * 16 + 4 * g + rr][ct * 16 + c] = h;
                    T[w][1][mt * 16 + 4 * g + rr][ct * 16 + c] = l;
                }
            }
        }
        asm volatile("s_waitcnt lgkmcnt(0)" ::: "memory");
        // L2 partial: K-chunk = ch
        bf16x8 w2h[4], w2l[4];
#pragma unroll
        for (int nt = 0; nt < 4; ++nt) {
            w2h[nt] = *(const bf16x8*)&w2f[(((ch * 4 + nt) * 2 + 0) * 64 + lane) * 8];
            w2l[nt] = *(const bf16x8*)&w2f[(((ch * 4 + nt) * 2 + 1) * 64 + lane) * 8];
        }
#pragma unroll
        for (int mt = 0; mt < 4; ++mt) {
            bf16x8 ah = *(const bf16x8*)&T[w][0][mt * 16 + c][8 * g];
            bf16x8 al = *(const bf16x8*)&T[w][1][mt * 16 + c][8 * g];
#pragma unroll
            for (int nt = 0; nt < 4; ++nt) {
                acc2[mt][nt] = mm(ah, w2h[nt], acc2[mt][nt]);
                acc2[mt][nt] = mm(ah, w2l[nt], acc2[mt][nt]);
                acc2[mt][nt] = mm(al, w2h[nt], acc2[mt][nt]);
            }
        }
        asm volatile("s_waitcnt lgkmcnt(0)" ::: "memory");
    }

    // ---------------- L3 (two K-chunks from acc2) -------------------------
    f32x4 acc3[4][2];
#pragma unroll
    for (int mt = 0; mt < 4; ++mt) { acc3[mt][0] = zero4; acc3[mt][1] = zero4; }

#pragma unroll
    for (int kc = 0; kc < 2; ++kc) {
#pragma unroll
        for (int q = 0; q < 2; ++q) {
            const int nt2 = kc * 2 + q;
            const float bias2 = b2[nt2 * 16 + c];
#pragma unroll
            for (int mt = 0; mt < 4; ++mt) {
#pragma unroll
                for (int rr = 0; rr < 4; ++rr) {
                    float v = fmaxf(acc2[mt][nt2][rr] + bias2, 0.0f);
                    unsigned short h, l;
                    split2(v, h, l);
                    T[w][0][mt * 16 + 4 * g + rr][q * 16 + c] = h;
                    T[w][1][mt * 16 + 4 * g + rr][q * 16 + c] = l;
                }
            }
        }
        asm volatile("s_waitcnt lgkmcnt(0)" ::: "memory");
        bf16x8 w3h[2], w3l[2];
#pragma unroll
        for (int nt = 0; nt < 2; ++nt) {
            w3h[nt] = *(const bf16x8*)&w3f[(((kc * 2 + nt) * 2 + 0) * 64 + lane) * 8];
            w3l[nt] = *(const bf16x8*)&w3f[(((kc * 2 + nt) * 2 + 1) * 64 + lane) * 8];
        }
#pragma unroll
        for (int mt = 0; mt < 4; ++mt) {
            bf16x8 ah = *(const bf16x8*)&T[w][0][mt * 16 + c][8 * g];
            bf16x8 al = *(const bf16x8*)&T[w][1][mt * 16 + c][8 * g];
#pragma unroll
            for (int nt = 0; nt < 2; ++nt) {
                acc3[mt][nt] = mm(ah, w3h[nt], acc3[mt][nt]);
                acc3[mt][nt] = mm(ah, w3l[nt], acc3[mt][nt]);
                acc3[mt][nt] = mm(al, w3h[nt], acc3[mt][nt]);
            }
        }
        asm volatile("s_waitcnt lgkmcnt(0)" ::: "memory");
    }

    // ---------------- L3 relu -> f32 LDS -> per-thread L4 -----------------
    // stride 33 dwords: bank = (33*lane + k) % 32 = (lane + k) % 32 -> no conflict
    float* a3f = (float*)&T[w][0][0][0];  // [64][33] f32 view (8448 B < 10240)
#pragma unroll
    for (int nt = 0; nt < 2; ++nt) {
        const float bias3 = b3[nt * 16 + c];
#pragma unroll
        for (int mt = 0; mt < 4; ++mt)
#pragma unroll
            for (int rr = 0; rr < 4; ++rr)
                a3f[(mt * 16 + 4 * g + rr) * 33 + nt * 16 + c] =
                    fmaxf(acc3[mt][nt][rr] + bias3, 0.0f);
    }
    asm volatile("s_waitcnt lgkmcnt(0)" ::: "memory");
    float o = b4[0];
#pragma unroll
    for (int k = 0; k < 32; ++k) o = fmaf(a3f[lane * 33 + k], W4[k], o);
    out[b] = o;
}

extern "C" void kernel_launch(void* const* d_in, const int* in_sizes, int n_in,
                              void* d_out, int out_size, void* d_ws, size_t ws_size,
                              hipStream_t stream) {
    const float* x    = (const float*)d_in[0];
    const float* W_ih = (const float*)d_in[1];
    const float* W_hh = (const float*)d_in[2];
    const float* b_ih = (const float*)d_in[3];
    const float* b_hh = (const float*)d_in[4];
    const float* W1   = (const float*)d_in[5];
    const float* b1   = (const float*)d_in[6];
    const float* W2   = (const float*)d_in[7];
    const float* b2   = (const float*)d_in[8];
    const float* W3   = (const float*)d_in[9];
    const float* b3   = (const float*)d_in[10];
    const float* W4   = (const float*)d_in[11];
    const float* b4   = (const float*)d_in[12];
    float* out = (float*)d_out;

    unsigned short* wf = (unsigned short*)d_ws;  // 28672 shorts = 57344 B

    hipLaunchKernelGGL(prep_frags, dim3(112), dim3(256), 0, stream, W1, W2, W3, wf);

    const int B = in_sizes[0] / 40;  // [B, 10, 4]
    hipLaunchKernelGGL(lstm_mlp_mfma, dim3(B / 256), dim3(256), 0, stream,
                       x, W_ih, W_hh, b_ih, b_hh, wf, b1, b2, b3, W4, b4, out);
}

// Round 6
// 328.533 us; speedup vs baseline: 1.8154x; 1.0020x over previous
//
#include <hip/hip_runtime.h>
#include <hip/hip_bf16.h>

// ---------------------------------------------------------------------------
// LSTM (H=2,I=4,T=10) on VALU + MLP 20->128->64->32->1 on MFMA (split-bf16).
// One thread per element; each wave owns 64 rows (M=64).
// MLP GEMMs: D = A(act) x B(weights), mfma_f32_16x16x32_bf16, 3 mfma/tile
// (Ah*Bh + Ah*Bl + Al*Bh). Weights pre-split + pre-fragmented into d_ws.
// Inter-layer transpose via per-wave LDS buffer T (wave-local).
// R6 change: wave-local phase fences are COMPILER-ONLY (empty asm w/ memory
// clobber) instead of HW `s_waitcnt lgkmcnt(0)` drains. Correctness: the LDS
// pipe executes a wave's DS ops in program order (RAW/WAR safe), and the
// compiler auto-inserts counted lgkmcnt waits before MFMAs consume ds_read
// data. Structure/numerics otherwise identical to R5.
// ---------------------------------------------------------------------------

typedef __attribute__((ext_vector_type(8))) short bf16x8;
typedef __attribute__((ext_vector_type(4))) float f32x4;

#define PHASE_FENCE() asm volatile("" ::: "memory")

__device__ __forceinline__ float fsig(float x) { return __builtin_amdgcn_rcpf(1.0f + __expf(-x)); }
__device__ __forceinline__ float ftanh(float x) { return 1.0f - 2.0f * __builtin_amdgcn_rcpf(__expf(2.0f * x) + 1.0f); }

__device__ __forceinline__ unsigned short bf_bits(__hip_bfloat16 h) {
    union { __hip_bfloat16 b; unsigned short u; } cv; cv.b = h; return cv.u;
}
// split v into hi(bf16) + lo(bf16), native cvt (RNE)
__device__ __forceinline__ void split2(float v, unsigned short& h, unsigned short& l) {
    __hip_bfloat16 hb = __float2bfloat16(v);
    float hf = __bfloat162float(hb);
    h = bf_bits(hb);
    l = bf_bits(__float2bfloat16(v - hf));
}
__device__ __forceinline__ f32x4 mm(bf16x8 a, bf16x8 b, f32x4 c) {
    return __builtin_amdgcn_mfma_f32_16x16x32_bf16(a, b, c, 0, 0, 0);
}

// --- prep: split W1/W2/W3 into hi/lo bf16 B-fragments in ws ---
// layout (shorts): w1f [8nt][2pl][64][8] @0 (8192)
//                  w2f [4kt][4nt][2pl][64][8] @8192 (16384)
//                  w3f [2kt][2nt][2pl][64][8] @24576 (4096)   total 28672
__global__ void prep_frags(const float* __restrict__ W1,
                           const float* __restrict__ W2,
                           const float* __restrict__ W3,
                           unsigned short* __restrict__ wf) {
    int idx = blockIdx.x * 256 + threadIdx.x;
    if (idx >= 28672) return;
    float v = 0.0f; int pl;
    if (idx < 8192) {
        int r = idx;
        int j = r & 7, lane = (r >> 3) & 63; pl = (r >> 9) & 1; int nt = r >> 10;
        int cc = lane & 15, gg = lane >> 4;
        int k = 8 * gg + j, n = nt * 16 + cc;
        v = (k < 20) ? W1[n * 20 + k] : 0.0f;   // K padded 20->32 with zeros
    } else if (idx < 24576) {
        int r = idx - 8192;
        int j = r & 7, lane = (r >> 3) & 63; pl = (r >> 9) & 1;
        int nt = (r >> 10) & 3, kt = r >> 12;
        int cc = lane & 15, gg = lane >> 4;
        int k = kt * 32 + 8 * gg + j, n = nt * 16 + cc;
        v = W2[n * 128 + k];
    } else {
        int r = idx - 24576;
        int j = r & 7, lane = (r >> 3) & 63; pl = (r >> 9) & 1;
        int nt = (r >> 10) & 1, kt = r >> 11;
        int cc = lane & 15, gg = lane >> 4;
        int k = kt * 32 + 8 * gg + j, n = nt * 16 + cc;
        v = W3[n * 64 + k];
    }
    unsigned short hi, lo;
    split2(v, hi, lo);
    wf[idx] = pl ? lo : hi;
}

__global__ __launch_bounds__(256, 3) void lstm_mlp_mfma(
    const float* __restrict__ x,
    const float* __restrict__ W_ih, const float* __restrict__ W_hh,
    const float* __restrict__ b_ih, const float* __restrict__ b_hh,
    const unsigned short* __restrict__ wf,
    const float* __restrict__ b1, const float* __restrict__ b2,
    const float* __restrict__ b3,
    const float* __restrict__ W4, const float* __restrict__ b4,
    float* __restrict__ out)
{
    // per-wave transpose buffer: [plane][row][40] shorts; 10240 B/wave
    __shared__ unsigned short T[4][2][64][40];
    const int tid = threadIdx.x;
    const int w = tid >> 6, lane = tid & 63;
    const int c = lane & 15, g = lane >> 4;
    const long long b = (long long)blockIdx.x * 256 + tid;

    // ---------------- LSTM (VALU, identical math to verified baseline) ----
    float wih[8][4], whh[8][2], lbias[8];
#pragma unroll
    for (int k = 0; k < 8; ++k) {
#pragma unroll
        for (int i = 0; i < 4; ++i) wih[k][i] = W_ih[k * 4 + i];
        whh[k][0] = W_hh[k * 2 + 0];
        whh[k][1] = W_hh[k * 2 + 1];
        lbias[k] = b_ih[k] + b_hh[k];
    }
    const float4* xb = reinterpret_cast<const float4*>(x) + b * 10;
    float h0 = 0.0f, h1 = 0.0f, c0 = 0.0f, c1v = 0.0f;
    float hist[20];
#pragma unroll
    for (int t = 0; t < 10; ++t) {
        const float4 xv = xb[t];
        float gg[8];
#pragma unroll
        for (int k = 0; k < 8; ++k) {
            float a = lbias[k];
            a = fmaf(wih[k][0], xv.x, a);
            a = fmaf(wih[k][1], xv.y, a);
            a = fmaf(wih[k][2], xv.z, a);
            a = fmaf(wih[k][3], xv.w, a);
            a = fmaf(whh[k][0], h0, a);
            a = fmaf(whh[k][1], h1, a);
            gg[k] = a;
        }
        const float i0 = fsig(gg[0]), i1 = fsig(gg[1]);
        const float f0 = fsig(gg[2]), f1 = fsig(gg[3]);
        const float g0 = ftanh(gg[4]), g1 = ftanh(gg[5]);
        const float o0 = fsig(gg[6]), o1 = fsig(gg[7]);
        c0 = fmaf(f0, c0, i0 * g0);
        c1v = fmaf(f1, c1v, i1 * g1);
        h0 = o0 * ftanh(c0);
        h1 = o1 * ftanh(c1v);
        hist[t * 2 + 0] = h0;
        hist[t * 2 + 1] = h1;
    }

    // ---------------- stage hist rows (split bf16, K=32 zero-padded) ------
#pragma unroll
    for (int i = 0; i < 10; ++i) {
        unsigned short hA, lA, hB, lB;
        split2(hist[2 * i], hA, lA);
        split2(hist[2 * i + 1], hB, lB);
        *(unsigned*)&T[w][0][lane][2 * i] = (unsigned)hA | ((unsigned)hB << 16);
        *(unsigned*)&T[w][1][lane][2 * i] = (unsigned)lA | ((unsigned)lB << 16);
    }
#pragma unroll
    for (int i = 0; i < 6; ++i) {
        *(unsigned*)&T[w][0][lane][20 + 2 * i] = 0u;
        *(unsigned*)&T[w][1][lane][20 + 2 * i] = 0u;
    }
    PHASE_FENCE();

    // A1 fragments held in registers for all chunks
    bf16x8 a1h[4], a1l[4];
#pragma unroll
    for (int mt = 0; mt < 4; ++mt) {
        a1h[mt] = *(const bf16x8*)&T[w][0][mt * 16 + c][8 * g];
        a1l[mt] = *(const bf16x8*)&T[w][1][mt * 16 + c][8 * g];
    }
    PHASE_FENCE();

    const unsigned short* w1f = wf;
    const unsigned short* w2f = wf + 8192;
    const unsigned short* w3f = wf + 24576;
    const f32x4 zero4 = {0.f, 0.f, 0.f, 0.f};

    f32x4 acc2[4][4];
#pragma unroll
    for (int mt = 0; mt < 4; ++mt)
#pragma unroll
        for (int nt = 0; nt < 4; ++nt) acc2[mt][nt] = zero4;

    // ---------------- L1 (chunked) + L2 accumulate ------------------------
#pragma unroll
    for (int ch = 0; ch < 4; ++ch) {
        // L1 for cols [ch*32, ch*32+32) -> transpose buffer
#pragma unroll
        for (int ct = 0; ct < 2; ++ct) {
            const int nt1 = ch * 2 + ct;
            bf16x8 wh = *(const bf16x8*)&w1f[((nt1 * 2 + 0) * 64 + lane) * 8];
            bf16x8 wl = *(const bf16x8*)&w1f[((nt1 * 2 + 1) * 64 + lane) * 8];
            const float bias1 = b1[nt1 * 16 + c];
#pragma unroll
            for (int mt = 0; mt < 4; ++mt) {
                f32x4 c1 = zero4;
                c1 = mm(a1h[mt], wh, c1);
                c1 = mm(a1h[mt], wl, c1);
                c1 = mm(a1l[mt], wh, c1);
#pragma unroll
                for (int rr = 0; rr < 4; ++rr) {
                    float v = fmaxf(c1[rr] + bias1, 0.0f);
                    unsigned short h, l;
                    split2(v, h, l);
                    T[w][0][mt * 16 + 4 * g + rr][ct * 16 + c] = h;
                    T[w][1][mt * 16 + 4 * g + rr][ct * 16 + c] = l;
                }
            }
        }
        PHASE_FENCE();
        // L2 partial: K-chunk = ch
        bf16x8 w2h[4], w2l[4];
#pragma unroll
        for (int nt = 0; nt < 4; ++nt) {
            w2h[nt] = *(const bf16x8*)&w2f[(((ch * 4 + nt) * 2 + 0) * 64 + lane) * 8];
            w2l[nt] = *(const bf16x8*)&w2f[(((ch * 4 + nt) * 2 + 1) * 64 + lane) * 8];
        }
#pragma unroll
        for (int mt = 0; mt < 4; ++mt) {
            bf16x8 ah = *(const bf16x8*)&T[w][0][mt * 16 + c][8 * g];
            bf16x8 al = *(const bf16x8*)&T[w][1][mt * 16 + c][8 * g];
#pragma unroll
            for (int nt = 0; nt < 4; ++nt) {
                acc2[mt][nt] = mm(ah, w2h[nt], acc2[mt][nt]);
                acc2[mt][nt] = mm(ah, w2l[nt], acc2[mt][nt]);
                acc2[mt][nt] = mm(al, w2h[nt], acc2[mt][nt]);
            }
        }
        PHASE_FENCE();
    }

    // ---------------- L3 (two K-chunks from acc2) -------------------------
    f32x4 acc3[4][2];
#pragma unroll
    for (int mt = 0; mt < 4; ++mt) { acc3[mt][0] = zero4; acc3[mt][1] = zero4; }

#pragma unroll
    for (int kc = 0; kc < 2; ++kc) {
#pragma unroll
        for (int q = 0; q < 2; ++q) {
            const int nt2 = kc * 2 + q;
            const float bias2 = b2[nt2 * 16 + c];
#pragma unroll
            for (int mt = 0; mt < 4; ++mt) {
#pragma unroll
                for (int rr = 0; rr < 4; ++rr) {
                    float v = fmaxf(acc2[mt][nt2][rr] + bias2, 0.0f);
                    unsigned short h, l;
                    split2(v, h, l);
                    T[w][0][mt * 16 + 4 * g + rr][q * 16 + c] = h;
                    T[w][1][mt * 16 + 4 * g + rr][q * 16 + c] = l;
                }
            }
        }
        PHASE_FENCE();
        bf16x8 w3h[2], w3l[2];
#pragma unroll
        for (int nt = 0; nt < 2; ++nt) {
            w3h[nt] = *(const bf16x8*)&w3f[(((kc * 2 + nt) * 2 + 0) * 64 + lane) * 8];
            w3l[nt] = *(const bf16x8*)&w3f[(((kc * 2 + nt) * 2 + 1) * 64 + lane) * 8];
        }
#pragma unroll
        for (int mt = 0; mt < 4; ++mt) {
            bf16x8 ah = *(const bf16x8*)&T[w][0][mt * 16 + c][8 * g];
            bf16x8 al = *(const bf16x8*)&T[w][1][mt * 16 + c][8 * g];
#pragma unroll
            for (int nt = 0; nt < 2; ++nt) {
                acc3[mt][nt] = mm(ah, w3h[nt], acc3[mt][nt]);
                acc3[mt][nt] = mm(ah, w3l[nt], acc3[mt][nt]);
                acc3[mt][nt] = mm(al, w3h[nt], acc3[mt][nt]);
            }
        }
        PHASE_FENCE();
    }

    // ---------------- L3 relu -> f32 LDS -> per-thread L4 -----------------
    // stride 33 dwords: bank = (33*lane + k) % 32 = (lane + k) % 32 -> no conflict
    float* a3f = (float*)&T[w][0][0][0];  // [64][33] f32 view (8448 B < 10240)
#pragma unroll
    for (int nt = 0; nt < 2; ++nt) {
        const float bias3 = b3[nt * 16 + c];
#pragma unroll
        for (int mt = 0; mt < 4; ++mt)
#pragma unroll
            for (int rr = 0; rr < 4; ++rr)
                a3f[(mt * 16 + 4 * g + rr) * 33 + nt * 16 + c] =
                    fmaxf(acc3[mt][nt][rr] + bias3, 0.0f);
    }
    PHASE_FENCE();
    float o = b4[0];
#pragma unroll
    for (int k = 0; k < 32; ++k) o = fmaf(a3f[lane * 33 + k], W4[k], o);
    out[b] = o;
}

extern "C" void kernel_launch(void* const* d_in, const int* in_sizes, int n_in,
                              void* d_out, int out_size, void* d_ws, size_t ws_size,
                              hipStream_t stream) {
    const float* x    = (const float*)d_in[0];
    const float* W_ih = (const float*)d_in[1];
    const float* W_hh = (const float*)d_in[2];
    const float* b_ih = (const float*)d_in[3];
    const float* b_hh = (const float*)d_in[4];
    const float* W1   = (const float*)d_in[5];
    const float* b1   = (const float*)d_in[6];
    const float* W2   = (const float*)d_in[7];
    const float* b2   = (const float*)d_in[8];
    const float* W3   = (const float*)d_in[9];
    const float* b3   = (const float*)d_in[10];
    const float* W4   = (const float*)d_in[11];
    const float* b4   = (const float*)d_in[12];
    float* out = (float*)d_out;

    unsigned short* wf = (unsigned short*)d_ws;  // 28672 shorts = 57344 B

    hipLaunchKernelGGL(prep_frags, dim3(112), dim3(256), 0, stream, W1, W2, W3, wf);

    const int B = in_sizes[0] / 40;  // [B, 10, 4]
    hipLaunchKernelGGL(lstm_mlp_mfma, dim3(B / 256), dim3(256), 0, stream,
                       x, W_ih, W_hh, b_ih, b_hh, wf, b1, b2, b3, W4, b4, out);
}

// Round 7
// 302.745 us; speedup vs baseline: 1.9700x; 1.0852x over previous
//
#include <hip/hip_runtime.h>
#include <hip/hip_bf16.h>

// ---------------------------------------------------------------------------
// LSTM (H=2,I=4,T=10) on VALU + MLP 20->128->64->32->1 on MFMA.
// One thread per element; each wave owns 64 rows (M=64).
// R7 change: activations are SINGLE bf16 (hi only); weights remain split
// hi/lo bf16 (2 MFMAs per tile: Ah*Bh + Ah*Bl). Weight quantization error
// ~2^-17 (negligible); activation error ~2^-9 relative, ~3 quantization
// points -> well under the 2%-relative threshold. Halves split2 VALU work,
// halves activation LDS traffic, cuts MFMA count 336->224 per thread.
// Structure otherwise identical to R6 (validated ordering: wave-local
// in-order DS pipe + compiler fences only).
// ---------------------------------------------------------------------------

typedef __attribute__((ext_vector_type(8))) short bf16x8;
typedef __attribute__((ext_vector_type(4))) float f32x4;

#define PHASE_FENCE() asm volatile("" ::: "memory")

__device__ __forceinline__ float fsig(float x) { return __builtin_amdgcn_rcpf(1.0f + __expf(-x)); }
__device__ __forceinline__ float ftanh(float x) { return 1.0f - 2.0f * __builtin_amdgcn_rcpf(__expf(2.0f * x) + 1.0f); }

__device__ __forceinline__ unsigned short bf_bits(__hip_bfloat16 h) {
    union { __hip_bfloat16 b; unsigned short u; } cv; cv.b = h; return cv.u;
}
__device__ __forceinline__ unsigned short bf_hi(float v) {
    return bf_bits(__float2bfloat16(v));   // native v_cvt, RNE
}
// full split (weights prep only)
__device__ __forceinline__ void split2(float v, unsigned short& h, unsigned short& l) {
    __hip_bfloat16 hb = __float2bfloat16(v);
    float hf = __bfloat162float(hb);
    h = bf_bits(hb);
    l = bf_bits(__float2bfloat16(v - hf));
}
__device__ __forceinline__ f32x4 mm(bf16x8 a, bf16x8 b, f32x4 c) {
    return __builtin_amdgcn_mfma_f32_16x16x32_bf16(a, b, c, 0, 0, 0);
}

// --- prep: split W1/W2/W3 into hi/lo bf16 B-fragments in ws ---
// layout (shorts): w1f [8nt][2pl][64][8] @0 (8192)
//                  w2f [4kt][4nt][2pl][64][8] @8192 (16384)
//                  w3f [2kt][2nt][2pl][64][8] @24576 (4096)   total 28672
__global__ void prep_frags(const float* __restrict__ W1,
                           const float* __restrict__ W2,
                           const float* __restrict__ W3,
                           unsigned short* __restrict__ wf) {
    int idx = blockIdx.x * 256 + threadIdx.x;
    if (idx >= 28672) return;
    float v = 0.0f; int pl;
    if (idx < 8192) {
        int r = idx;
        int j = r & 7, lane = (r >> 3) & 63; pl = (r >> 9) & 1; int nt = r >> 10;
        int cc = lane & 15, gg = lane >> 4;
        int k = 8 * gg + j, n = nt * 16 + cc;
        v = (k < 20) ? W1[n * 20 + k] : 0.0f;   // K padded 20->32 with zeros
    } else if (idx < 24576) {
        int r = idx - 8192;
        int j = r & 7, lane = (r >> 3) & 63; pl = (r >> 9) & 1;
        int nt = (r >> 10) & 3, kt = r >> 12;
        int cc = lane & 15, gg = lane >> 4;
        int k = kt * 32 + 8 * gg + j, n = nt * 16 + cc;
        v = W2[n * 128 + k];
    } else {
        int r = idx - 24576;
        int j = r & 7, lane = (r >> 3) & 63; pl = (r >> 9) & 1;
        int nt = (r >> 10) & 1, kt = r >> 11;
        int cc = lane & 15, gg = lane >> 4;
        int k = kt * 32 + 8 * gg + j, n = nt * 16 + cc;
        v = W3[n * 64 + k];
    }
    unsigned short hi, lo;
    split2(v, hi, lo);
    wf[idx] = pl ? lo : hi;
}

__global__ __launch_bounds__(256, 3) void lstm_mlp_mfma(
    const float* __restrict__ x,
    const float* __restrict__ W_ih, const float* __restrict__ W_hh,
    const float* __restrict__ b_ih, const float* __restrict__ b_hh,
    const unsigned short* __restrict__ wf,
    const float* __restrict__ b1, const float* __restrict__ b2,
    const float* __restrict__ b3,
    const float* __restrict__ W4, const float* __restrict__ b4,
    float* __restrict__ out)
{
    // per-wave buffer: plane 0 = bf16 activations [64][40]; plane 1 spare
    // (keeps space for the [64][33] f32 view in the L4 tail).
    __shared__ unsigned short T[4][2][64][40];
    const int tid = threadIdx.x;
    const int w = tid >> 6, lane = tid & 63;
    const int c = lane & 15, g = lane >> 4;
    const long long b = (long long)blockIdx.x * 256 + tid;

    // ---------------- LSTM (VALU, identical math to verified baseline) ----
    float wih[8][4], whh[8][2], lbias[8];
#pragma unroll
    for (int k = 0; k < 8; ++k) {
#pragma unroll
        for (int i = 0; i < 4; ++i) wih[k][i] = W_ih[k * 4 + i];
        whh[k][0] = W_hh[k * 2 + 0];
        whh[k][1] = W_hh[k * 2 + 1];
        lbias[k] = b_ih[k] + b_hh[k];
    }
    const float4* xb = reinterpret_cast<const float4*>(x) + b * 10;
    float h0 = 0.0f, h1 = 0.0f, c0 = 0.0f, c1v = 0.0f;
    float hist[20];
#pragma unroll
    for (int t = 0; t < 10; ++t) {
        const float4 xv = xb[t];
        float gg[8];
#pragma unroll
        for (int k = 0; k < 8; ++k) {
            float a = lbias[k];
            a = fmaf(wih[k][0], xv.x, a);
            a = fmaf(wih[k][1], xv.y, a);
            a = fmaf(wih[k][2], xv.z, a);
            a = fmaf(wih[k][3], xv.w, a);
            a = fmaf(whh[k][0], h0, a);
            a = fmaf(whh[k][1], h1, a);
            gg[k] = a;
        }
        const float i0 = fsig(gg[0]), i1 = fsig(gg[1]);
        const float f0 = fsig(gg[2]), f1 = fsig(gg[3]);
        const float g0 = ftanh(gg[4]), g1 = ftanh(gg[5]);
        const float o0 = fsig(gg[6]), o1 = fsig(gg[7]);
        c0 = fmaf(f0, c0, i0 * g0);
        c1v = fmaf(f1, c1v, i1 * g1);
        h0 = o0 * ftanh(c0);
        h1 = o1 * ftanh(c1v);
        hist[t * 2 + 0] = h0;
        hist[t * 2 + 1] = h1;
    }

    // ---------------- stage hist rows (bf16 hi, K=32 zero-padded) ---------
#pragma unroll
    for (int i = 0; i < 10; ++i) {
        unsigned short hA = bf_hi(hist[2 * i]);
        unsigned short hB = bf_hi(hist[2 * i + 1]);
        *(unsigned*)&T[w][0][lane][2 * i] = (unsigned)hA | ((unsigned)hB << 16);
    }
#pragma unroll
    for (int i = 0; i < 6; ++i)
        *(unsigned*)&T[w][0][lane][20 + 2 * i] = 0u;
    PHASE_FENCE();

    // A1 fragments held in registers for all chunks
    bf16x8 a1h[4];
#pragma unroll
    for (int mt = 0; mt < 4; ++mt)
        a1h[mt] = *(const bf16x8*)&T[w][0][mt * 16 + c][8 * g];
    PHASE_FENCE();

    const unsigned short* w1f = wf;
    const unsigned short* w2f = wf + 8192;
    const unsigned short* w3f = wf + 24576;
    const f32x4 zero4 = {0.f, 0.f, 0.f, 0.f};

    f32x4 acc2[4][4];
#pragma unroll
    for (int mt = 0; mt < 4; ++mt)
#pragma unroll
        for (int nt = 0; nt < 4; ++nt) acc2[mt][nt] = zero4;

    // ---------------- L1 (chunked) + L2 accumulate ------------------------
#pragma unroll
    for (int ch = 0; ch < 4; ++ch) {
        // L1 for cols [ch*32, ch*32+32) -> plane-0 buffer
#pragma unroll
        for (int ct = 0; ct < 2; ++ct) {
            const int nt1 = ch * 2 + ct;
            bf16x8 wh = *(const bf16x8*)&w1f[((nt1 * 2 + 0) * 64 + lane) * 8];
            bf16x8 wl = *(const bf16x8*)&w1f[((nt1 * 2 + 1) * 64 + lane) * 8];
            const float bias1 = b1[nt1 * 16 + c];
#pragma unroll
            for (int mt = 0; mt < 4; ++mt) {
                f32x4 c1 = zero4;
                c1 = mm(a1h[mt], wh, c1);
                c1 = mm(a1h[mt], wl, c1);
#pragma unroll
                for (int rr = 0; rr < 4; ++rr) {
                    float v = fmaxf(c1[rr] + bias1, 0.0f);
                    T[w][0][mt * 16 + 4 * g + rr][ct * 16 + c] = bf_hi(v);
                }
            }
        }
        PHASE_FENCE();
        // L2 partial: K-chunk = ch
        bf16x8 w2h[4], w2l[4];
#pragma unroll
        for (int nt = 0; nt < 4; ++nt) {
            w2h[nt] = *(const bf16x8*)&w2f[(((ch * 4 + nt) * 2 + 0) * 64 + lane) * 8];
            w2l[nt] = *(const bf16x8*)&w2f[(((ch * 4 + nt) * 2 + 1) * 64 + lane) * 8];
        }
#pragma unroll
        for (int mt = 0; mt < 4; ++mt) {
            bf16x8 ah = *(const bf16x8*)&T[w][0][mt * 16 + c][8 * g];
#pragma unroll
            for (int nt = 0; nt < 4; ++nt) {
                acc2[mt][nt] = mm(ah, w2h[nt], acc2[mt][nt]);
                acc2[mt][nt] = mm(ah, w2l[nt], acc2[mt][nt]);
            }
        }
        PHASE_FENCE();
    }

    // ---------------- L3 (two K-chunks from acc2) -------------------------
    f32x4 acc3[4][2];
#pragma unroll
    for (int mt = 0; mt < 4; ++mt) { acc3[mt][0] = zero4; acc3[mt][1] = zero4; }

#pragma unroll
    for (int kc = 0; kc < 2; ++kc) {
#pragma unroll
        for (int q = 0; q < 2; ++q) {
            const int nt2 = kc * 2 + q;
            const float bias2 = b2[nt2 * 16 + c];
#pragma unroll
            for (int mt = 0; mt < 4; ++mt) {
#pragma unroll
                for (int rr = 0; rr < 4; ++rr) {
                    float v = fmaxf(acc2[mt][nt2][rr] + bias2, 0.0f);
                    T[w][0][mt * 16 + 4 * g + rr][q * 16 + c] = bf_hi(v);
                }
            }
        }
        PHASE_FENCE();
        bf16x8 w3h[2], w3l[2];
#pragma unroll
        for (int nt = 0; nt < 2; ++nt) {
            w3h[nt] = *(const bf16x8*)&w3f[(((kc * 2 + nt) * 2 + 0) * 64 + lane) * 8];
            w3l[nt] = *(const bf16x8*)&w3f[(((kc * 2 + nt) * 2 + 1) * 64 + lane) * 8];
        }
#pragma unroll
        for (int mt = 0; mt < 4; ++mt) {
            bf16x8 ah = *(const bf16x8*)&T[w][0][mt * 16 + c][8 * g];
#pragma unroll
            for (int nt = 0; nt < 2; ++nt) {
                acc3[mt][nt] = mm(ah, w3h[nt], acc3[mt][nt]);
                acc3[mt][nt] = mm(ah, w3l[nt], acc3[mt][nt]);
            }
        }
        PHASE_FENCE();
    }

    // ---------------- L3 relu -> f32 LDS -> per-thread L4 -----------------
    // stride 33 dwords: bank = (33*lane + k) % 32 = (lane + k) % 32 -> no conflict
    float* a3f = (float*)&T[w][0][0][0];  // [64][33] f32 view (8448 B < 10240)
#pragma unroll
    for (int nt = 0; nt < 2; ++nt) {
        const float bias3 = b3[nt * 16 + c];
#pragma unroll
        for (int mt = 0; mt < 4; ++mt)
#pragma unroll
            for (int rr = 0; rr < 4; ++rr)
                a3f[(mt * 16 + 4 * g + rr) * 33 + nt * 16 + c] =
                    fmaxf(acc3[mt][nt][rr] + bias3, 0.0f);
    }
    PHASE_FENCE();
    float o = b4[0];
#pragma unroll
    for (int k = 0; k < 32; ++k) o = fmaf(a3f[lane * 33 + k], W4[k], o);
    out[b] = o;
}

extern "C" void kernel_launch(void* const* d_in, const int* in_sizes, int n_in,
                              void* d_out, int out_size, void* d_ws, size_t ws_size,
                              hipStream_t stream) {
    const float* x    = (const float*)d_in[0];
    const float* W_ih = (const float*)d_in[1];
    const float* W_hh = (const float*)d_in[2];
    const float* b_ih = (const float*)d_in[3];
    const float* b_hh = (const float*)d_in[4];
    const float* W1   = (const float*)d_in[5];
    const float* b1   = (const float*)d_in[6];
    const float* W2   = (const float*)d_in[7];
    const float* b2   = (const float*)d_in[8];
    const float* W3   = (const float*)d_in[9];
    const float* b3   = (const float*)d_in[10];
    const float* W4   = (const float*)d_in[11];
    const float* b4   = (const float*)d_in[12];
    float* out = (float*)d_out;

    unsigned short* wf = (unsigned short*)d_ws;  // 28672 shorts = 57344 B

    hipLaunchKernelGGL(prep_frags, dim3(112), dim3(256), 0, stream, W1, W2, W3, wf);

    const int B = in_sizes[0] / 40;  // [B, 10, 4]
    hipLaunchKernelGGL(lstm_mlp_mfma, dim3(B / 256), dim3(256), 0, stream,
                       x, W_ih, W_hh, b_ih, b_hh, wf, b1, b2, b3, W4, b4, out);
}